// Round 1
// baseline (174.547 us; speedup 1.0000x reference)
//
#include <hip/hip_runtime.h>

// Problem: B=2048, N=512, C=64, L=2, O=8192
//   connections = argmax_c weights[c,l,o]          -> [L,O]
//   sel[l,o]    = indices[connections[l,o], l, o]  -> [L,O]
//   out[b,l,o]  = x[b, sel[l,o]]                   -> [B,L,O] fp32 (128 MiB)

#define BB 2048
#define NN 512
#define CC 64
#define LL 2
#define OO 8192
#define LO (LL * OO)  // 16384

__global__ void sel_kernel(const float* __restrict__ weights,
                           const int* __restrict__ indices,
                           int* __restrict__ sel) {
    int t = blockIdx.x * blockDim.x + threadIdx.x;  // t = l*O + o
    if (t >= LO) return;
    float best = weights[t];
    int bestc = 0;
#pragma unroll 8
    for (int c = 1; c < CC; ++c) {
        float w = weights[(size_t)c * LO + t];
        if (w > best) { best = w; bestc = c; }  // strict > keeps first-max (JAX argmax)
    }
    sel[t] = indices[(size_t)bestc * LO + t];
}

__global__ void __launch_bounds__(256)
gather_kernel(const float* __restrict__ x,
              const int* __restrict__ sel,
              float* __restrict__ out) {
    __shared__ float xrow[NN];
    const int b = blockIdx.x;
    const float* xp = x + (size_t)b * NN;
    // stage this batch row's 512 floats into LDS
    for (int i = threadIdx.x; i < NN; i += 256) xrow[i] = xp[i];
    __syncthreads();

    float* op = out + (size_t)b * LO;
    // 16384 outputs / (256 threads * 4/thread) = 16 iterations
#pragma unroll 4
    for (int i = 0; i < LO / (256 * 4); ++i) {
        int base = i * 1024 + threadIdx.x * 4;
        int4 s = *reinterpret_cast<const int4*>(sel + base);
        float4 v;
        v.x = xrow[s.x];
        v.y = xrow[s.y];
        v.z = xrow[s.z];
        v.w = xrow[s.w];
        *reinterpret_cast<float4*>(op + base) = v;
    }
}

extern "C" void kernel_launch(void* const* d_in, const int* in_sizes, int n_in,
                              void* d_out, int out_size, void* d_ws, size_t ws_size,
                              hipStream_t stream) {
    const float* x       = (const float*)d_in[0];   // [B, N]
    const float* weights = (const float*)d_in[1];   // [C, L, O]
    const int*   indices = (const int*)d_in[2];     // [C, L, O]
    float*       out     = (float*)d_out;           // [B, L, O]
    int*         sel     = (int*)d_ws;              // [L*O] scratch (64 KiB)

    sel_kernel<<<LO / 256, 256, 0, stream>>>(weights, indices, sel);
    gather_kernel<<<BB, 256, 0, stream>>>(x, sel, out);
}

// Round 2
// 150.832 us; speedup vs baseline: 1.1572x; 1.1572x over previous
//
#include <hip/hip_runtime.h>

// Problem: B=2048, N=512, C=64, L=2, O=8192
//   connections = argmax_c weights[c,l,o]          -> [L,O]
//   sel[l,o]    = indices[connections[l,o], l, o]  -> [L,O]
//   out[b,l,o]  = x[b, sel[l,o]]                   -> [B,L,O] fp32 (128 MiB)
//
// Floor: 128 MiB output writes @ ~6.3 TB/s ≈ 21 us. Strategy: amortize the
// sel table and x staging across 8 batch rows per block so sel L2 traffic
// drops 128 MiB -> 16 MiB and each sel int4 register feeds 8 float4 stores.

#define BB 2048
#define NN 512
#define CC 64
#define LL 2
#define OO 8192
#define LO (LL * OO)       // 16384
#define ROWS 8             // batch rows per block
#define CHUNK 4096         // lo elements per block
#define NCHUNK (LO / CHUNK)            // 4
#define ITERS (CHUNK / (256 * 4))      // 4 iterations of int4/float4 per thread

__global__ void sel_kernel(const float* __restrict__ weights,
                           const int* __restrict__ indices,
                           int* __restrict__ sel) {
    int t = blockIdx.x * blockDim.x + threadIdx.x;  // t = l*O + o
    if (t >= LO) return;
    float best = weights[t];
    int bestc = 0;
#pragma unroll 8
    for (int c = 1; c < CC; ++c) {
        float w = weights[(size_t)c * LO + t];
        if (w > best) { best = w; bestc = c; }  // strict > keeps first-max (JAX argmax)
    }
    sel[t] = indices[(size_t)bestc * LO + t];
}

__global__ void __launch_bounds__(256)
gather_kernel(const float* __restrict__ x,
              const int* __restrict__ sel,
              float* __restrict__ out) {
    __shared__ float xrows[ROWS * NN];   // 16 KiB: 8 contiguous batch rows of x

    const int rg    = blockIdx.x / NCHUNK;       // row group [0, 256)
    const int chunk = blockIdx.x % NCHUNK;       // lo chunk  [0, 4)
    const int b0    = rg * ROWS;

    // Stage 8 contiguous x rows (4096 floats) with coalesced float4 loads.
    const float4* xp4 = reinterpret_cast<const float4*>(x + (size_t)b0 * NN);
    float4* sh4 = reinterpret_cast<float4*>(xrows);
#pragma unroll
    for (int i = 0; i < (ROWS * NN / 4) / 256; ++i)   // 4 iterations
        sh4[i * 256 + threadIdx.x] = xp4[i * 256 + threadIdx.x];
    __syncthreads();

    const int* selp = sel + chunk * CHUNK;
    float* op = out + (size_t)b0 * LO + chunk * CHUNK;

#pragma unroll
    for (int i = 0; i < ITERS; ++i) {
        const int base = i * 1024 + threadIdx.x * 4;
        int4 s = *reinterpret_cast<const int4*>(selp + base);
#pragma unroll
        for (int r = 0; r < ROWS; ++r) {
            const float* row = xrows + r * NN;
            float4 v;
            v.x = row[s.x];
            v.y = row[s.y];
            v.z = row[s.z];
            v.w = row[s.w];
            *reinterpret_cast<float4*>(op + (size_t)r * LO + base) = v;
        }
    }
}

extern "C" void kernel_launch(void* const* d_in, const int* in_sizes, int n_in,
                              void* d_out, int out_size, void* d_ws, size_t ws_size,
                              hipStream_t stream) {
    const float* x       = (const float*)d_in[0];   // [B, N]
    const float* weights = (const float*)d_in[1];   // [C, L, O]
    const int*   indices = (const int*)d_in[2];     // [C, L, O]
    float*       out     = (float*)d_out;           // [B, L, O]
    int*         sel     = (int*)d_ws;              // [L*O] scratch (64 KiB)

    sel_kernel<<<LO / 256, 256, 0, stream>>>(weights, indices, sel);
    gather_kernel<<<(BB / ROWS) * NCHUNK, 256, 0, stream>>>(x, sel, out);
}